// Round 4
// baseline (639.597 us; speedup 1.0000x reference)
//
#include <hip/hip_runtime.h>
#include <math.h>

#define NN 8192
#define FF 256
#define ALPHA 0.2f
#define SS 4                 // j-segments
#define JSEG (NN / SS)       // 2048
#define STEPS (JSEG / 32)    // 64

typedef __bf16 bf16x8 __attribute__((ext_vector_type(8)));
typedef __bf16 bf16x4 __attribute__((ext_vector_type(4)));
typedef float  f32x4  __attribute__((ext_vector_type(4)));

__device__ __forceinline__ void dma16(const void* g, void* l) {
    __builtin_amdgcn_global_load_lds((const __attribute__((address_space(1))) void*)g,
                                     (__attribute__((address_space(3))) void*)l,
                                     16, 0, 0);
}

// raw-pipeline sync primitives: no vmcnt(0) drain at the barrier
#define VMCNT4   asm volatile("s_waitcnt vmcnt(4)" ::: "memory")
#define LGKM0    asm volatile("s_waitcnt lgkmcnt(0)" ::: "memory")
#define BARRIER  asm volatile("s_barrier" ::: "memory")
#define FENCE    asm volatile("" ::: "memory")

// ---------------- K0: WT[hl][n][k] bf16 hi/lo from W[k][n] fp32 -----------
__global__ __launch_bounds__(256) void k0_wt(const float* __restrict__ W,
                                             __bf16* __restrict__ WT) {
    __shared__ float ts[64][65];
    const int t = threadIdx.x;
    const int k0 = blockIdx.x * 64;
    const int n0 = blockIdx.y * 64;
    #pragma unroll
    for (int r = 0; r < 4; ++r) {
        int krow = r * 16 + (t >> 4);
        int nc4 = (t & 15) * 4;
        *(float4*)&ts[krow][nc4] = *(const float4*)&W[(size_t)(k0 + krow) * FF + n0 + nc4];
    }
    __syncthreads();
    const int nloc = t >> 2;
    const int kc = (t & 3) * 16;
    union { bf16x8 v[2]; __bf16 e[16]; } hi, lo;
    #pragma unroll
    for (int u = 0; u < 16; ++u) {
        float x = ts[kc + u][nloc];
        __bf16 h1 = (__bf16)x;
        hi.e[u] = h1;
        lo.e[u] = (__bf16)(x - (float)h1);
    }
    size_t base = (size_t)(n0 + nloc) * FF + k0 + kc;
    *(bf16x8*)&WT[base] = hi.v[0];
    *(bf16x8*)&WT[base + 8] = hi.v[1];
    size_t lbase = (size_t)FF * FF + base;
    *(bf16x8*)&WT[lbase] = lo.v[0];
    *(bf16x8*)&WT[lbase + 8] = lo.v[1];
}

// ---------------- K1: MFMA h-tile -> hT(hi/lo, transposed) + src/dst ------
__global__ __launch_bounds__(256) void k1_h(const float* __restrict__ X,
                                            const __bf16* __restrict__ WT,
                                            const float* __restrict__ a,
                                            __bf16* __restrict__ hT,
                                            float* __restrict__ src,
                                            float* __restrict__ dst) {
    __shared__ __bf16 ax[2][32][40];
    __shared__ float hs[32][264];
    __shared__ float red[2][4][32];
    const int t = threadIdx.x;
    const int i0 = blockIdx.x * 32;
    const int l = t & 63, wv = t >> 6, ln = l & 15, g = l >> 4;
    f32x4 acc[2][4];
    #pragma unroll
    for (int mt = 0; mt < 2; ++mt)
        #pragma unroll
        for (int nt = 0; nt < 4; ++nt)
            acc[mt][nt] = (f32x4){0.f, 0.f, 0.f, 0.f};

    for (int ks = 0; ks < 8; ++ks) {
        const int k0 = ks * 32;
        {
            int row = t >> 3, c4 = (t & 7) * 4;
            float4 xv = *(const float4*)&X[(size_t)(i0 + row) * FF + k0 + c4];
            bf16x4 hi4, lo4;
            float xs_[4] = {xv.x, xv.y, xv.z, xv.w};
            #pragma unroll
            for (int u = 0; u < 4; ++u) {
                __bf16 h1 = (__bf16)xs_[u];
                hi4[u] = h1;
                lo4[u] = (__bf16)(xs_[u] - (float)h1);
            }
            *(bf16x4*)&ax[0][row][c4] = hi4;
            *(bf16x4*)&ax[1][row][c4] = lo4;
        }
        __syncthreads();
        bf16x8 ah[2], al[2];
        ah[0] = *(bf16x8*)&ax[0][ln][g * 8];
        ah[1] = *(bf16x8*)&ax[0][16 + ln][g * 8];
        al[0] = *(bf16x8*)&ax[1][ln][g * 8];
        al[1] = *(bf16x8*)&ax[1][16 + ln][g * 8];
        #pragma unroll
        for (int nt = 0; nt < 4; ++nt) {
            const int n = wv * 64 + nt * 16 + ln;
            bf16x8 bh8 = *(const bf16x8*)&WT[(size_t)n * FF + k0 + g * 8];
            bf16x8 bl8 = *(const bf16x8*)&WT[(size_t)(FF + n) * FF + k0 + g * 8];
            #pragma unroll
            for (int mt = 0; mt < 2; ++mt) {
                acc[mt][nt] = __builtin_amdgcn_mfma_f32_16x16x32_bf16(ah[mt], bh8, acc[mt][nt], 0, 0, 0);
                acc[mt][nt] = __builtin_amdgcn_mfma_f32_16x16x32_bf16(ah[mt], bl8, acc[mt][nt], 0, 0, 0);
                acc[mt][nt] = __builtin_amdgcn_mfma_f32_16x16x32_bf16(al[mt], bh8, acc[mt][nt], 0, 0, 0);
            }
        }
        __syncthreads();
    }
    float an[4], ad[4];
    #pragma unroll
    for (int nt = 0; nt < 4; ++nt) {
        an[nt] = a[wv * 64 + nt * 16 + ln];
        ad[nt] = a[FF + wv * 64 + nt * 16 + ln];
    }
    float sp[2][4], dp[2][4];
    #pragma unroll
    for (int mt = 0; mt < 2; ++mt)
        #pragma unroll
        for (int rg = 0; rg < 4; ++rg) { sp[mt][rg] = 0.f; dp[mt][rg] = 0.f; }
    #pragma unroll
    for (int mt = 0; mt < 2; ++mt)
        #pragma unroll
        for (int nt = 0; nt < 4; ++nt)
            #pragma unroll
            for (int rg = 0; rg < 4; ++rg) {
                float v = acc[mt][nt][rg];
                hs[mt * 16 + g * 4 + rg][wv * 64 + nt * 16 + ln] = v;
                sp[mt][rg] += v * an[nt];
                dp[mt][rg] += v * ad[nt];
            }
    #pragma unroll
    for (int mk = 1; mk < 16; mk <<= 1)
        #pragma unroll
        for (int mt = 0; mt < 2; ++mt)
            #pragma unroll
            for (int rg = 0; rg < 4; ++rg) {
                sp[mt][rg] += __shfl_xor(sp[mt][rg], mk);
                dp[mt][rg] += __shfl_xor(dp[mt][rg], mk);
            }
    if (ln == 0) {
        #pragma unroll
        for (int mt = 0; mt < 2; ++mt)
            #pragma unroll
            for (int rg = 0; rg < 4; ++rg) {
                red[0][wv][mt * 16 + g * 4 + rg] = sp[mt][rg];
                red[1][wv][mt * 16 + g * 4 + rg] = dp[mt][rg];
            }
    }
    __syncthreads();
    if (t < 32) {
        src[i0 + t] = red[0][0][t] + red[0][1][t] + red[0][2][t] + red[0][3][t];
        dst[i0 + t] = red[1][0][t] + red[1][1][t] + red[1][2][t] + red[1][3][t];
    }
    {
        const int f = t;
        #pragma unroll
        for (int jc = 0; jc < 4; ++jc) {
            union { bf16x8 v; __bf16 e[8]; } hi, lo;
            #pragma unroll
            for (int u = 0; u < 8; ++u) {
                float x = hs[jc * 8 + u][f];
                __bf16 h1 = (__bf16)x;
                hi.e[u] = h1;
                lo.e[u] = (__bf16)(x - (float)h1);
            }
            *(bf16x8*)&hT[(size_t)f * NN + i0 + jc * 8] = hi.v;
            *(bf16x8*)&hT[(size_t)(FF + f) * NN + i0 + jc * 8] = lo.v;
        }
    }
}

// ---------------- K2b: maxd = max_j dst_j ---------------------------------
__global__ __launch_bounds__(256) void k2b_max(const float* __restrict__ dst,
                                               float* __restrict__ maxd) {
    __shared__ float red[256];
    float m = -1e30f;
    #pragma unroll
    for (int r = 0; r < NN / 1024; ++r) {
        float4 v = *(const float4*)&dst[(r * 256 + threadIdx.x) * 4];
        m = fmaxf(m, fmaxf(fmaxf(v.x, v.y), fmaxf(v.z, v.w)));
    }
    red[threadIdx.x] = m;
    __syncthreads();
    for (int s = 128; s > 0; s >>= 1) {
        if (threadIdx.x < s) red[threadIdx.x] = fmaxf(red[threadIdx.x], red[threadIdx.x + s]);
        __syncthreads();
    }
    if (threadIdx.x == 0) maxd[0] = red[0];
}

// ---------------- K3: raw-barrier pipelined MFMA attention GEMM -----------
// Per step issue order (hand-counted, uniform every iter incl. clamped tail):
//   [2] w(s) from regs -> ds_write wA[p]
//   [3] adj/dst(s+2) loads x4        (prefetch distance 2)
//   [4] s_waitcnt vmcnt(4)           drains DMA(s) x8 (oldest), leaves adj x4
//       s_waitcnt lgkmcnt(0); s_barrier     <- NO vmcnt(0) drain
//   [6] DMA(s+1) x8 -> bh[p^1]; FENCE pins issue order
//   [8] ds_read + 32 MFMA on bh[p], wA[p]
__global__ __launch_bounds__(256, 2) void k3_attn(const int* __restrict__ adj,
                                                  const __bf16* __restrict__ hT,
                                                  const float* __restrict__ src,
                                                  const float* __restrict__ dst,
                                                  const float* __restrict__ maxd,
                                                  float* __restrict__ num,
                                                  float* __restrict__ den) {
    __shared__ __bf16 bh[2][2048 * 8];
    __shared__ __bf16 wA[2][64][40];
    __shared__ float dl[64][4];
    const int t = threadIdx.x;
    const int l = t & 63, wv = t >> 6, ln = l & 15, g = l >> 4;
    const int it = blockIdx.x & 127;
    const int seg = blockIdx.x >> 7;
    const int i0 = it * 64;
    const int jbeg = seg * JSEG;
    const int p_i = t >> 2, p_q = t & 3;
    const float maxdv = maxd[0];
    const float src_r = src[i0 + p_i];
    const float e0 = src_r + maxdv;
    const float m_r = e0 > 0.f ? e0 : ALPHA * e0;

    int rowbase[8], cb[8];
    #pragma unroll
    for (int r = 0; r < 8; ++r) {
        int cbase = r * 256 + wv * 64;
        int c = cbase + l;
        int hl = c >> 10;
        int f = (c >> 2) & 255;
        int pc = c & 3;
        int jc = pc ^ ((f >> 1) & 3);
        rowbase[r] = (hl * FF + f) * NN + jc * 8;
        cb[r] = __builtin_amdgcn_readfirstlane(cbase);
    }
    const int* arow = adj + (size_t)(i0 + p_i) * NN + p_q * 8;

    int4 A0[2], A1[2];
    float4 D0[2], D1[2];
    // prologue: adj(0), DMA(0), adj(1)  (order matters for vmcnt math)
    A0[0] = *(const int4*)(arow + jbeg);
    A1[0] = *(const int4*)(arow + jbeg + 4);
    D0[0] = *(const float4*)&dst[jbeg + p_q * 8];
    D1[0] = *(const float4*)&dst[jbeg + p_q * 8 + 4];
    FENCE;
    #pragma unroll
    for (int r = 0; r < 8; ++r)
        dma16(&hT[rowbase[r] + jbeg], &bh[0][cb[r] * 8]);
    FENCE;
    A0[1] = *(const int4*)(arow + jbeg + 32);
    A1[1] = *(const int4*)(arow + jbeg + 32 + 4);
    D0[1] = *(const float4*)&dst[jbeg + 32 + p_q * 8];
    D1[1] = *(const float4*)&dst[jbeg + 32 + p_q * 8 + 4];

    float den_reg = 0.f;
    f32x4 acc[4][4];
    #pragma unroll
    for (int mt = 0; mt < 4; ++mt)
        #pragma unroll
        for (int nt = 0; nt < 4; ++nt)
            acc[mt][nt] = (f32x4){0.f, 0.f, 0.f, 0.f};

    for (int s = 0; s < STEPS; ++s) {
        const int p = s & 1;
        // [2] w-compute from slot p
        {
            const int av[8] = {A0[p].x, A0[p].y, A0[p].z, A0[p].w,
                               A1[p].x, A1[p].y, A1[p].z, A1[p].w};
            const float dv[8] = {D0[p].x, D0[p].y, D0[p].z, D0[p].w,
                                 D1[p].x, D1[p].y, D1[p].z, D1[p].w};
            union { bf16x8 v; __bf16 e[8]; } wu;
            #pragma unroll
            for (int u = 0; u < 8; ++u) {
                float e = src_r + dv[u];
                e = e > 0.f ? e : ALPHA * e;
                float w = (av[u] > 0) ? __expf(e - m_r) : 0.f;
                den_reg += w;
                wu.e[u] = (__bf16)w;
            }
            *(bf16x8*)&wA[p][p_i][p_q * 8] = wu.v;
        }
        // [3] prefetch adj/dst(s+2) into slot p (clamped, always 4 loads)
        {
            const int jn = (s + 2 < STEPS) ? jbeg + (s + 2) * 32 : jbeg;
            A0[p] = *(const int4*)(arow + jn);
            A1[p] = *(const int4*)(arow + jn + 4);
            D0[p] = *(const float4*)&dst[jn + p_q * 8];
            D1[p] = *(const float4*)&dst[jn + p_q * 8 + 4];
        }
        // [4] fine-grained drain + raw barrier
        VMCNT4;
        LGKM0;
        BARRIER;
        // [6] DMA(s+1) -> bh[p^1] (clamped, always 8)
        {
            const int j1 = (s + 1 < STEPS) ? jbeg + (s + 1) * 32 : jbeg;
            #pragma unroll
            for (int r = 0; r < 8; ++r)
                dma16(&hT[rowbase[r] + j1], &bh[p ^ 1][cb[r] * 8]);
        }
        FENCE;
        // [8] MFMA on bh[p], wA[p]
        bf16x8 af[4];
        #pragma unroll
        for (int mt = 0; mt < 4; ++mt)
            af[mt] = *(bf16x8*)&wA[p][mt * 16 + ln][g * 8];
        #pragma unroll
        for (int nt = 0; nt < 4; ++nt) {
            const int f = wv * 64 + nt * 16 + ln;
            const int sw = (f >> 1) & 3;
            #pragma unroll
            for (int hl = 0; hl < 2; ++hl) {
                const int chunk = (hl * FF + f) * 4 + (g ^ sw);
                bf16x8 bfr = *(bf16x8*)&bh[p][chunk * 8];
                #pragma unroll
                for (int mt = 0; mt < 4; ++mt)
                    acc[mt][nt] = __builtin_amdgcn_mfma_f32_16x16x32_bf16(
                        af[mt], bfr, acc[mt][nt], 0, 0, 0);
            }
        }
    }
    // epilogue
    #pragma unroll
    for (int mt = 0; mt < 4; ++mt)
        #pragma unroll
        for (int nt = 0; nt < 4; ++nt)
            #pragma unroll
            for (int rg = 0; rg < 4; ++rg)
                num[((size_t)seg * NN + i0 + mt * 16 + g * 4 + rg) * FF
                    + wv * 64 + nt * 16 + ln] = acc[mt][nt][rg];
    dl[p_i][p_q] = den_reg;
    __syncthreads();
    if (t < 64) den[(size_t)seg * NN + i0 + t] = dl[t][0] + dl[t][1] + dl[t][2] + dl[t][3];
}

// ---------------- K4: out = relu( sum_s num / sum_s den ) -----------------
__global__ __launch_bounds__(256) void k4_out(const float* __restrict__ num,
                                              const float* __restrict__ den,
                                              float* __restrict__ out) {
    size_t f4 = (size_t)blockIdx.x * 256 + threadIdx.x;
    int i = (int)(f4 >> 6);
    int c4 = (int)(f4 & 63) << 2;
    float4 s = make_float4(0.f, 0.f, 0.f, 0.f);
    float d = 0.f;
    #pragma unroll
    for (int sg = 0; sg < SS; ++sg) {
        float4 v = *(const float4*)&num[((size_t)sg * NN + i) * FF + c4];
        s.x += v.x; s.y += v.y; s.z += v.z; s.w += v.w;
        d += den[(size_t)sg * NN + i];
    }
    float inv = 1.f / d;
    float4 o;
    o.x = fmaxf(s.x * inv, 0.f);
    o.y = fmaxf(s.y * inv, 0.f);
    o.z = fmaxf(s.z * inv, 0.f);
    o.w = fmaxf(s.w * inv, 0.f);
    *(float4*)&out[(size_t)i * FF + c4] = o;
}

extern "C" void kernel_launch(void* const* d_in, const int* in_sizes, int n_in,
                              void* d_out, int out_size, void* d_ws, size_t ws_size,
                              hipStream_t stream) {
    const float* X  = (const float*)d_in[0];
    const int*  adj = (const int*)d_in[1];
    const float* W  = (const float*)d_in[2];
    const float* a  = (const float*)d_in[3];
    float* out = (float*)d_out;
    char* ws = (char*)d_ws;

    const size_t off_hT   = 0;
    const size_t off_wt   = off_hT + (size_t)2 * FF * NN * 2;
    const size_t off_src  = off_wt + (size_t)2 * FF * FF * 2;
    const size_t off_dst  = off_src + (size_t)NN * 4;
    const size_t off_maxd = off_dst + (size_t)NN * 4;
    const size_t off_num  = off_maxd + 256;
    const size_t off_den  = off_num + (size_t)SS * NN * FF * 4;

    __bf16* hT_ws = (__bf16*)(ws + off_hT);
    __bf16* wt_ws = (__bf16*)(ws + off_wt);
    float* src_ws = (float*)(ws + off_src);
    float* dst_ws = (float*)(ws + off_dst);
    float* maxd   = (float*)(ws + off_maxd);
    float* num_ws = (float*)(ws + off_num);
    float* den_ws = (float*)(ws + off_den);

    k0_wt<<<dim3(FF / 64, FF / 64), 256, 0, stream>>>(W, wt_ws);
    k1_h<<<NN / 32, 256, 0, stream>>>(X, wt_ws, a, hT_ws, src_ws, dst_ws);
    k2b_max<<<1, 256, 0, stream>>>(dst_ws, maxd);
    k3_attn<<<(NN / 64) * SS, 256, 0, stream>>>(adj, hT_ws, src_ws, dst_ws, maxd,
                                                num_ws, den_ws);
    k4_out<<<(NN * FF / 4) / 256, 256, 0, stream>>>(num_ws, den_ws, out);
}

// Round 5
// 486.003 us; speedup vs baseline: 1.3160x; 1.3160x over previous
//
#include <hip/hip_runtime.h>
#include <math.h>

#define NN 8192
#define FF 256
#define ALPHA 0.2f
#define SS 4                 // j-segments
#define JSEG (NN / SS)       // 2048
#define STEPS (JSEG / 32)    // 64 (even)

typedef __bf16 bf16x8 __attribute__((ext_vector_type(8)));
typedef __bf16 bf16x4 __attribute__((ext_vector_type(4)));
typedef float  f32x4  __attribute__((ext_vector_type(4)));

__device__ __forceinline__ void dma16(const void* g, void* l) {
    __builtin_amdgcn_global_load_lds((const __attribute__((address_space(1))) void*)g,
                                     (__attribute__((address_space(3))) void*)l,
                                     16, 0, 0);
}

#define VMCNT4   asm volatile("s_waitcnt vmcnt(4)" ::: "memory")
#define LGKM0    asm volatile("s_waitcnt lgkmcnt(0)" ::: "memory")
#define BARRIER  asm volatile("s_barrier" ::: "memory")
#define FENCE    asm volatile("" ::: "memory")

// ---------------- K0: WT[hl][n][k] bf16 hi/lo from W[k][n] fp32 -----------
__global__ __launch_bounds__(256) void k0_wt(const float* __restrict__ W,
                                             __bf16* __restrict__ WT) {
    __shared__ float ts[64][65];
    const int t = threadIdx.x;
    const int k0 = blockIdx.x * 64;
    const int n0 = blockIdx.y * 64;
    #pragma unroll
    for (int r = 0; r < 4; ++r) {
        int krow = r * 16 + (t >> 4);
        int nc4 = (t & 15) * 4;
        *(float4*)&ts[krow][nc4] = *(const float4*)&W[(size_t)(k0 + krow) * FF + n0 + nc4];
    }
    __syncthreads();
    const int nloc = t >> 2;
    const int kc = (t & 3) * 16;
    union { bf16x8 v[2]; __bf16 e[16]; } hi, lo;
    #pragma unroll
    for (int u = 0; u < 16; ++u) {
        float x = ts[kc + u][nloc];
        __bf16 h1 = (__bf16)x;
        hi.e[u] = h1;
        lo.e[u] = (__bf16)(x - (float)h1);
    }
    size_t base = (size_t)(n0 + nloc) * FF + k0 + kc;
    *(bf16x8*)&WT[base] = hi.v[0];
    *(bf16x8*)&WT[base + 8] = hi.v[1];
    size_t lbase = (size_t)FF * FF + base;
    *(bf16x8*)&WT[lbase] = lo.v[0];
    *(bf16x8*)&WT[lbase + 8] = lo.v[1];
}

// ---------------- K1: MFMA h-tile -> hT(hi/lo, transposed) + src/dst ------
__global__ __launch_bounds__(256) void k1_h(const float* __restrict__ X,
                                            const __bf16* __restrict__ WT,
                                            const float* __restrict__ a,
                                            __bf16* __restrict__ hT,
                                            float* __restrict__ src,
                                            float* __restrict__ dst) {
    __shared__ __bf16 ax[2][32][40];
    __shared__ float hs[32][264];
    __shared__ float red[2][4][32];
    const int t = threadIdx.x;
    const int i0 = blockIdx.x * 32;
    const int l = t & 63, wv = t >> 6, ln = l & 15, g = l >> 4;
    f32x4 acc[2][4];
    #pragma unroll
    for (int mt = 0; mt < 2; ++mt)
        #pragma unroll
        for (int nt = 0; nt < 4; ++nt)
            acc[mt][nt] = (f32x4){0.f, 0.f, 0.f, 0.f};

    for (int ks = 0; ks < 8; ++ks) {
        const int k0 = ks * 32;
        {
            int row = t >> 3, c4 = (t & 7) * 4;
            float4 xv = *(const float4*)&X[(size_t)(i0 + row) * FF + k0 + c4];
            bf16x4 hi4, lo4;
            float xs_[4] = {xv.x, xv.y, xv.z, xv.w};
            #pragma unroll
            for (int u = 0; u < 4; ++u) {
                __bf16 h1 = (__bf16)xs_[u];
                hi4[u] = h1;
                lo4[u] = (__bf16)(xs_[u] - (float)h1);
            }
            *(bf16x4*)&ax[0][row][c4] = hi4;
            *(bf16x4*)&ax[1][row][c4] = lo4;
        }
        __syncthreads();
        bf16x8 ah[2], al[2];
        ah[0] = *(bf16x8*)&ax[0][ln][g * 8];
        ah[1] = *(bf16x8*)&ax[0][16 + ln][g * 8];
        al[0] = *(bf16x8*)&ax[1][ln][g * 8];
        al[1] = *(bf16x8*)&ax[1][16 + ln][g * 8];
        #pragma unroll
        for (int nt = 0; nt < 4; ++nt) {
            const int n = wv * 64 + nt * 16 + ln;
            bf16x8 bh8 = *(const bf16x8*)&WT[(size_t)n * FF + k0 + g * 8];
            bf16x8 bl8 = *(const bf16x8*)&WT[(size_t)(FF + n) * FF + k0 + g * 8];
            #pragma unroll
            for (int mt = 0; mt < 2; ++mt) {
                acc[mt][nt] = __builtin_amdgcn_mfma_f32_16x16x32_bf16(ah[mt], bh8, acc[mt][nt], 0, 0, 0);
                acc[mt][nt] = __builtin_amdgcn_mfma_f32_16x16x32_bf16(ah[mt], bl8, acc[mt][nt], 0, 0, 0);
                acc[mt][nt] = __builtin_amdgcn_mfma_f32_16x16x32_bf16(al[mt], bh8, acc[mt][nt], 0, 0, 0);
            }
        }
        __syncthreads();
    }
    float an[4], ad[4];
    #pragma unroll
    for (int nt = 0; nt < 4; ++nt) {
        an[nt] = a[wv * 64 + nt * 16 + ln];
        ad[nt] = a[FF + wv * 64 + nt * 16 + ln];
    }
    float sp[2][4], dp[2][4];
    #pragma unroll
    for (int mt = 0; mt < 2; ++mt)
        #pragma unroll
        for (int rg = 0; rg < 4; ++rg) { sp[mt][rg] = 0.f; dp[mt][rg] = 0.f; }
    #pragma unroll
    for (int mt = 0; mt < 2; ++mt)
        #pragma unroll
        for (int nt = 0; nt < 4; ++nt)
            #pragma unroll
            for (int rg = 0; rg < 4; ++rg) {
                float v = acc[mt][nt][rg];
                hs[mt * 16 + g * 4 + rg][wv * 64 + nt * 16 + ln] = v;
                sp[mt][rg] += v * an[nt];
                dp[mt][rg] += v * ad[nt];
            }
    #pragma unroll
    for (int mk = 1; mk < 16; mk <<= 1)
        #pragma unroll
        for (int mt = 0; mt < 2; ++mt)
            #pragma unroll
            for (int rg = 0; rg < 4; ++rg) {
                sp[mt][rg] += __shfl_xor(sp[mt][rg], mk);
                dp[mt][rg] += __shfl_xor(dp[mt][rg], mk);
            }
    if (ln == 0) {
        #pragma unroll
        for (int mt = 0; mt < 2; ++mt)
            #pragma unroll
            for (int rg = 0; rg < 4; ++rg) {
                red[0][wv][mt * 16 + g * 4 + rg] = sp[mt][rg];
                red[1][wv][mt * 16 + g * 4 + rg] = dp[mt][rg];
            }
    }
    __syncthreads();
    if (t < 32) {
        src[i0 + t] = red[0][0][t] + red[0][1][t] + red[0][2][t] + red[0][3][t];
        dst[i0 + t] = red[1][0][t] + red[1][1][t] + red[1][2][t] + red[1][3][t];
    }
    {
        const int f = t;
        #pragma unroll
        for (int jc = 0; jc < 4; ++jc) {
            union { bf16x8 v; __bf16 e[8]; } hi, lo;
            #pragma unroll
            for (int u = 0; u < 8; ++u) {
                float x = hs[jc * 8 + u][f];
                __bf16 h1 = (__bf16)x;
                hi.e[u] = h1;
                lo.e[u] = (__bf16)(x - (float)h1);
            }
            *(bf16x8*)&hT[(size_t)f * NN + i0 + jc * 8] = hi.v;
            *(bf16x8*)&hT[(size_t)(FF + f) * NN + i0 + jc * 8] = lo.v;
        }
    }
}

// ---------------- K2b: maxd = max_j dst_j ---------------------------------
__global__ __launch_bounds__(256) void k2b_max(const float* __restrict__ dst,
                                               float* __restrict__ maxd) {
    __shared__ float red[256];
    float m = -1e30f;
    #pragma unroll
    for (int r = 0; r < NN / 1024; ++r) {
        float4 v = *(const float4*)&dst[(r * 256 + threadIdx.x) * 4];
        m = fmaxf(m, fmaxf(fmaxf(v.x, v.y), fmaxf(v.z, v.w)));
    }
    red[threadIdx.x] = m;
    __syncthreads();
    for (int s = 128; s > 0; s >>= 1) {
        if (threadIdx.x < s) red[threadIdx.x] = fmaxf(red[threadIdx.x], red[threadIdx.x + s]);
        __syncthreads();
    }
    if (threadIdx.x == 0) maxd[0] = red[0];
}

// ---------------- K3: raw-barrier pipelined MFMA attention GEMM -----------
// Manually unrolled x2 so prefetch slots are scalar regs (R4's array slots
// spilled to scratch: 505 MB phantom WRITE_SIZE). vmcnt ledger per half-step:
//   issue: adj(s+2)x4 -> FENCE -> vmcnt(4) [drains DMA(s)x8, leaves adj x4]
//   -> lgkmcnt(0) -> s_barrier -> DMA(s+1)x8 -> FENCE -> MFMA(s)
__global__ __launch_bounds__(256, 2) void k3_attn(const int* __restrict__ adj,
                                                  const __bf16* __restrict__ hT,
                                                  const float* __restrict__ src,
                                                  const float* __restrict__ dst,
                                                  const float* __restrict__ maxd,
                                                  float* __restrict__ num,
                                                  float* __restrict__ den) {
    __shared__ __bf16 bh[2][2048 * 8];
    __shared__ __bf16 wA[2][64][40];
    __shared__ float dl[64][4];
    const int t = threadIdx.x;
    const int l = t & 63, wv = t >> 6, ln = l & 15, g = l >> 4;
    const int it = blockIdx.x & 127;
    const int seg = blockIdx.x >> 7;
    const int i0 = it * 64;
    const int jbeg = seg * JSEG;
    const int p_i = t >> 2, p_q = t & 3;
    const float maxdv = maxd[0];
    const float src_r = src[i0 + p_i];
    const float e0 = src_r + maxdv;
    const float m_r = e0 > 0.f ? e0 : ALPHA * e0;

    int rowbase[8], cb[8];
    #pragma unroll
    for (int r = 0; r < 8; ++r) {
        int cbase = r * 256 + wv * 64;
        int c = cbase + l;
        int hl = c >> 10;
        int f = (c >> 2) & 255;
        int pc = c & 3;
        int jc = pc ^ ((f >> 1) & 3);
        rowbase[r] = (hl * FF + f) * NN + jc * 8;
        cb[r] = __builtin_amdgcn_readfirstlane(cbase);
    }
    const int* arow = adj + (size_t)(i0 + p_i) * NN + p_q * 8;
    const float* drow = dst + p_q * 8;

    // even/odd prefetch slots as scalars
    int4 a0e, a1e, a0o, a1o;
    float4 d0e, d1e, d0o, d1o;

    // prologue: adjE(0) x4, DMA(0) x8, adjO(1) x4  (issue order matters)
    a0e = *(const int4*)(arow + jbeg);
    a1e = *(const int4*)(arow + jbeg + 4);
    d0e = *(const float4*)(drow + jbeg);
    d1e = *(const float4*)(drow + jbeg + 4);
    FENCE;
    #pragma unroll
    for (int r = 0; r < 8; ++r)
        dma16(&hT[rowbase[r] + jbeg], &bh[0][cb[r] * 8]);
    FENCE;
    a0o = *(const int4*)(arow + jbeg + 32);
    a1o = *(const int4*)(arow + jbeg + 32 + 4);
    d0o = *(const float4*)(drow + jbeg + 32);
    d1o = *(const float4*)(drow + jbeg + 32 + 4);
    FENCE;

    float den_reg = 0.f;
    f32x4 acc[4][4];
    #pragma unroll
    for (int mt = 0; mt < 4; ++mt)
        #pragma unroll
        for (int nt = 0; nt < 4; ++nt)
            acc[mt][nt] = (f32x4){0.f, 0.f, 0.f, 0.f};

#define K3_WCOMP(A0_, A1_, D0_, D1_, P_)                                      \
    {                                                                         \
        const int av[8] = {A0_.x, A0_.y, A0_.z, A0_.w,                        \
                           A1_.x, A1_.y, A1_.z, A1_.w};                       \
        const float dv[8] = {D0_.x, D0_.y, D0_.z, D0_.w,                      \
                             D1_.x, D1_.y, D1_.z, D1_.w};                     \
        union { bf16x8 v; __bf16 e[8]; } wu;                                  \
        _Pragma("unroll")                                                     \
        for (int u = 0; u < 8; ++u) {                                         \
            float e = src_r + dv[u];                                          \
            e = e > 0.f ? e : ALPHA * e;                                      \
            float w = (av[u] > 0) ? __expf(e - m_r) : 0.f;                    \
            den_reg += w;                                                     \
            wu.e[u] = (__bf16)w;                                              \
        }                                                                     \
        *(bf16x8*)&wA[P_][p_i][p_q * 8] = wu.v;                               \
    }

#define K3_PREF(A0_, A1_, D0_, D1_, JN_)                                      \
    A0_ = *(const int4*)(arow + (JN_));                                       \
    A1_ = *(const int4*)(arow + (JN_) + 4);                                   \
    D0_ = *(const float4*)(drow + (JN_));                                     \
    D1_ = *(const float4*)(drow + (JN_) + 4);

#define K3_DMA(J1_, P_)                                                       \
    {                                                                         \
        _Pragma("unroll")                                                     \
        for (int r = 0; r < 8; ++r)                                           \
            dma16(&hT[rowbase[r] + (J1_)], &bh[P_][cb[r] * 8]);               \
    }

#define K3_MFMA(P_)                                                           \
    {                                                                         \
        bf16x8 af[4];                                                         \
        _Pragma("unroll")                                                     \
        for (int mt = 0; mt < 4; ++mt)                                        \
            af[mt] = *(bf16x8*)&wA[P_][mt * 16 + ln][g * 8];                  \
        _Pragma("unroll")                                                     \
        for (int nt = 0; nt < 4; ++nt) {                                      \
            const int f = wv * 64 + nt * 16 + ln;                             \
            const int sw = (f >> 1) & 3;                                      \
            _Pragma("unroll")                                                 \
            for (int hl = 0; hl < 2; ++hl) {                                  \
                const int chunk = (hl * FF + f) * 4 + (g ^ sw);               \
                bf16x8 bfr = *(bf16x8*)&bh[P_][chunk * 8];                    \
                _Pragma("unroll")                                             \
                for (int mt = 0; mt < 4; ++mt)                                \
                    acc[mt][nt] = __builtin_amdgcn_mfma_f32_16x16x32_bf16(    \
                        af[mt], bfr, acc[mt][nt], 0, 0, 0);                   \
            }                                                                 \
        }                                                                     \
    }

    for (int su = 0; su < STEPS; su += 2) {
        // ---- even half: s = su, uses even slots, wA[0], bh[0] ----
        K3_WCOMP(a0e, a1e, d0e, d1e, 0);
        {
            const int jn = (su + 2 < STEPS) ? jbeg + (su + 2) * 32 : jbeg;
            K3_PREF(a0e, a1e, d0e, d1e, jn);
        }
        FENCE; VMCNT4; LGKM0; BARRIER;
        K3_DMA(jbeg + (su + 1) * 32, 1);   // su+1 <= STEPS-1 always
        FENCE;
        K3_MFMA(0);
        // ---- odd half: s = su+1, odd slots, wA[1], bh[1] ----
        K3_WCOMP(a0o, a1o, d0o, d1o, 1);
        {
            const int jn = (su + 3 < STEPS) ? jbeg + (su + 3) * 32 : jbeg;
            K3_PREF(a0o, a1o, d0o, d1o, jn);
        }
        FENCE; VMCNT4; LGKM0; BARRIER;
        {
            const int j2 = (su + 2 < STEPS) ? jbeg + (su + 2) * 32 : jbeg;
            K3_DMA(j2, 0);
        }
        FENCE;
        K3_MFMA(1);
    }
    // epilogue
    __syncthreads();
    #pragma unroll
    for (int mt = 0; mt < 4; ++mt)
        #pragma unroll
        for (int nt = 0; nt < 4; ++nt)
            #pragma unroll
            for (int rg = 0; rg < 4; ++rg)
                num[((size_t)seg * NN + i0 + mt * 16 + g * 4 + rg) * FF
                    + wv * 64 + nt * 16 + ln] = acc[mt][nt][rg];
    dl[p_i][p_q] = den_reg;
    __syncthreads();
    if (t < 64) den[(size_t)seg * NN + i0 + t] = dl[t][0] + dl[t][1] + dl[t][2] + dl[t][3];
}

// ---------------- K4: out = relu( sum_s num / sum_s den ) -----------------
__global__ __launch_bounds__(256) void k4_out(const float* __restrict__ num,
                                              const float* __restrict__ den,
                                              float* __restrict__ out) {
    size_t f4 = (size_t)blockIdx.x * 256 + threadIdx.x;
    int i = (int)(f4 >> 6);
    int c4 = (int)(f4 & 63) << 2;
    float4 s = make_float4(0.f, 0.f, 0.f, 0.f);
    float d = 0.f;
    #pragma unroll
    for (int sg = 0; sg < SS; ++sg) {
        float4 v = *(const float4*)&num[((size_t)sg * NN + i) * FF + c4];
        s.x += v.x; s.y += v.y; s.z += v.z; s.w += v.w;
        d += den[(size_t)sg * NN + i];
    }
    float inv = 1.f / d;
    float4 o;
    o.x = fmaxf(s.x * inv, 0.f);
    o.y = fmaxf(s.y * inv, 0.f);
    o.z = fmaxf(s.z * inv, 0.f);
    o.w = fmaxf(s.w * inv, 0.f);
    *(float4*)&out[(size_t)i * FF + c4] = o;
}

extern "C" void kernel_launch(void* const* d_in, const int* in_sizes, int n_in,
                              void* d_out, int out_size, void* d_ws, size_t ws_size,
                              hipStream_t stream) {
    const float* X  = (const float*)d_in[0];
    const int*  adj = (const int*)d_in[1];
    const float* W  = (const float*)d_in[2];
    const float* a  = (const float*)d_in[3];
    float* out = (float*)d_out;
    char* ws = (char*)d_ws;

    const size_t off_hT   = 0;
    const size_t off_wt   = off_hT + (size_t)2 * FF * NN * 2;
    const size_t off_src  = off_wt + (size_t)2 * FF * FF * 2;
    const size_t off_dst  = off_src + (size_t)NN * 4;
    const size_t off_maxd = off_dst + (size_t)NN * 4;
    const size_t off_num  = off_maxd + 256;
    const size_t off_den  = off_num + (size_t)SS * NN * FF * 4;

    __bf16* hT_ws = (__bf16*)(ws + off_hT);
    __bf16* wt_ws = (__bf16*)(ws + off_wt);
    float* src_ws = (float*)(ws + off_src);
    float* dst_ws = (float*)(ws + off_dst);
    float* maxd   = (float*)(ws + off_maxd);
    float* num_ws = (float*)(ws + off_num);
    float* den_ws = (float*)(ws + off_den);

    k0_wt<<<dim3(FF / 64, FF / 64), 256, 0, stream>>>(W, wt_ws);
    k1_h<<<NN / 32, 256, 0, stream>>>(X, wt_ws, a, hT_ws, src_ws, dst_ws);
    k2b_max<<<1, 256, 0, stream>>>(dst_ws, maxd);
    k3_attn<<<(NN / 64) * SS, 256, 0, stream>>>(adj, hT_ws, src_ws, dst_ws, maxd,
                                                num_ws, den_ws);
    k4_out<<<(NN * FF / 4) / 256, 256, 0, stream>>>(num_ws, den_ws, out);
}

// Round 7
// 463.656 us; speedup vs baseline: 1.3795x; 1.0482x over previous
//
#include <hip/hip_runtime.h>
#include <math.h>

#define NN 8192
#define FF 256
#define ALPHA 0.2f
#define SS 4                 // j-segments
#define JSEG (NN / SS)       // 2048
#define STEPS (JSEG / 32)    // 64 (even)

typedef __bf16 bf16x8 __attribute__((ext_vector_type(8)));
typedef __bf16 bf16x4 __attribute__((ext_vector_type(4)));
typedef float  f32x4  __attribute__((ext_vector_type(4)));

__device__ __forceinline__ void dma16(const void* g, void* l) {
    __builtin_amdgcn_global_load_lds((const __attribute__((address_space(1))) void*)g,
                                     (__attribute__((address_space(3))) void*)l,
                                     16, 0, 0);
}

#define VMCNT4   asm volatile("s_waitcnt vmcnt(4)" ::: "memory")
#define LGKM0    asm volatile("s_waitcnt lgkmcnt(0)" ::: "memory")
#define BARRIER  asm volatile("s_barrier" ::: "memory")
#define FENCE    asm volatile("" ::: "memory")

// ---------------- K0: WT[hl][n][k] bf16 hi/lo from W[k][n] fp32 -----------
__global__ __launch_bounds__(256) void k0_wt(const float* __restrict__ W,
                                             __bf16* __restrict__ WT) {
    __shared__ float ts[64][65];
    const int t = threadIdx.x;
    const int k0 = blockIdx.x * 64;
    const int n0 = blockIdx.y * 64;
    #pragma unroll
    for (int r = 0; r < 4; ++r) {
        int krow = r * 16 + (t >> 4);
        int nc4 = (t & 15) * 4;
        *(float4*)&ts[krow][nc4] = *(const float4*)&W[(size_t)(k0 + krow) * FF + n0 + nc4];
    }
    __syncthreads();
    const int nloc = t >> 2;
    const int kc = (t & 3) * 16;
    union { bf16x8 v[2]; __bf16 e[16]; } hi, lo;
    #pragma unroll
    for (int u = 0; u < 16; ++u) {
        float x = ts[kc + u][nloc];
        __bf16 h1 = (__bf16)x;
        hi.e[u] = h1;
        lo.e[u] = (__bf16)(x - (float)h1);
    }
    size_t base = (size_t)(n0 + nloc) * FF + k0 + kc;
    *(bf16x8*)&WT[base] = hi.v[0];
    *(bf16x8*)&WT[base + 8] = hi.v[1];
    size_t lbase = (size_t)FF * FF + base;
    *(bf16x8*)&WT[lbase] = lo.v[0];
    *(bf16x8*)&WT[lbase + 8] = lo.v[1];
}

// ---------------- K1: MFMA h-tile -> hT(hi/lo, transposed) + src/dst ------
__global__ __launch_bounds__(256) void k1_h(const float* __restrict__ X,
                                            const __bf16* __restrict__ WT,
                                            const float* __restrict__ a,
                                            __bf16* __restrict__ hT,
                                            float* __restrict__ src,
                                            float* __restrict__ dst) {
    __shared__ __bf16 ax[2][32][40];
    __shared__ float hs[32][264];
    __shared__ float red[2][4][32];
    const int t = threadIdx.x;
    const int i0 = blockIdx.x * 32;
    const int l = t & 63, wv = t >> 6, ln = l & 15, g = l >> 4;
    f32x4 acc[2][4];
    #pragma unroll
    for (int mt = 0; mt < 2; ++mt)
        #pragma unroll
        for (int nt = 0; nt < 4; ++nt)
            acc[mt][nt] = (f32x4){0.f, 0.f, 0.f, 0.f};

    for (int ks = 0; ks < 8; ++ks) {
        const int k0 = ks * 32;
        {
            int row = t >> 3, c4 = (t & 7) * 4;
            float4 xv = *(const float4*)&X[(size_t)(i0 + row) * FF + k0 + c4];
            bf16x4 hi4, lo4;
            float xs_[4] = {xv.x, xv.y, xv.z, xv.w};
            #pragma unroll
            for (int u = 0; u < 4; ++u) {
                __bf16 h1 = (__bf16)xs_[u];
                hi4[u] = h1;
                lo4[u] = (__bf16)(xs_[u] - (float)h1);
            }
            *(bf16x4*)&ax[0][row][c4] = hi4;
            *(bf16x4*)&ax[1][row][c4] = lo4;
        }
        __syncthreads();
        bf16x8 ah[2], al[2];
        ah[0] = *(bf16x8*)&ax[0][ln][g * 8];
        ah[1] = *(bf16x8*)&ax[0][16 + ln][g * 8];
        al[0] = *(bf16x8*)&ax[1][ln][g * 8];
        al[1] = *(bf16x8*)&ax[1][16 + ln][g * 8];
        #pragma unroll
        for (int nt = 0; nt < 4; ++nt) {
            const int n = wv * 64 + nt * 16 + ln;
            bf16x8 bh8 = *(const bf16x8*)&WT[(size_t)n * FF + k0 + g * 8];
            bf16x8 bl8 = *(const bf16x8*)&WT[(size_t)(FF + n) * FF + k0 + g * 8];
            #pragma unroll
            for (int mt = 0; mt < 2; ++mt) {
                acc[mt][nt] = __builtin_amdgcn_mfma_f32_16x16x32_bf16(ah[mt], bh8, acc[mt][nt], 0, 0, 0);
                acc[mt][nt] = __builtin_amdgcn_mfma_f32_16x16x32_bf16(ah[mt], bl8, acc[mt][nt], 0, 0, 0);
                acc[mt][nt] = __builtin_amdgcn_mfma_f32_16x16x32_bf16(al[mt], bh8, acc[mt][nt], 0, 0, 0);
            }
        }
        __syncthreads();
    }
    float an[4], ad[4];
    #pragma unroll
    for (int nt = 0; nt < 4; ++nt) {
        an[nt] = a[wv * 64 + nt * 16 + ln];
        ad[nt] = a[FF + wv * 64 + nt * 16 + ln];
    }
    float sp[2][4], dp[2][4];
    #pragma unroll
    for (int mt = 0; mt < 2; ++mt)
        #pragma unroll
        for (int rg = 0; rg < 4; ++rg) { sp[mt][rg] = 0.f; dp[mt][rg] = 0.f; }
    #pragma unroll
    for (int mt = 0; mt < 2; ++mt)
        #pragma unroll
        for (int nt = 0; nt < 4; ++nt)
            #pragma unroll
            for (int rg = 0; rg < 4; ++rg) {
                float v = acc[mt][nt][rg];
                hs[mt * 16 + g * 4 + rg][wv * 64 + nt * 16 + ln] = v;
                sp[mt][rg] += v * an[nt];
                dp[mt][rg] += v * ad[nt];
            }
    #pragma unroll
    for (int mk = 1; mk < 16; mk <<= 1)
        #pragma unroll
        for (int mt = 0; mt < 2; ++mt)
            #pragma unroll
            for (int rg = 0; rg < 4; ++rg) {
                sp[mt][rg] += __shfl_xor(sp[mt][rg], mk);
                dp[mt][rg] += __shfl_xor(dp[mt][rg], mk);
            }
    if (ln == 0) {
        #pragma unroll
        for (int mt = 0; mt < 2; ++mt)
            #pragma unroll
            for (int rg = 0; rg < 4; ++rg) {
                red[0][wv][mt * 16 + g * 4 + rg] = sp[mt][rg];
                red[1][wv][mt * 16 + g * 4 + rg] = dp[mt][rg];
            }
    }
    __syncthreads();
    if (t < 32) {
        src[i0 + t] = red[0][0][t] + red[0][1][t] + red[0][2][t] + red[0][3][t];
        dst[i0 + t] = red[1][0][t] + red[1][1][t] + red[1][2][t] + red[1][3][t];
    }
    {
        const int f = t;
        #pragma unroll
        for (int jc = 0; jc < 4; ++jc) {
            union { bf16x8 v; __bf16 e[8]; } hi, lo;
            #pragma unroll
            for (int u = 0; u < 8; ++u) {
                float x = hs[jc * 8 + u][f];
                __bf16 h1 = (__bf16)x;
                hi.e[u] = h1;
                lo.e[u] = (__bf16)(x - (float)h1);
            }
            *(bf16x8*)&hT[(size_t)f * NN + i0 + jc * 8] = hi.v;
            *(bf16x8*)&hT[(size_t)(FF + f) * NN + i0 + jc * 8] = lo.v;
        }
    }
}

// ---------------- K2b: maxd = max_j dst_j ---------------------------------
__global__ __launch_bounds__(256) void k2b_max(const float* __restrict__ dst,
                                               float* __restrict__ maxd) {
    __shared__ float red[256];
    float m = -1e30f;
    #pragma unroll
    for (int r = 0; r < NN / 1024; ++r) {
        float4 v = *(const float4*)&dst[(r * 256 + threadIdx.x) * 4];
        m = fmaxf(m, fmaxf(fmaxf(v.x, v.y), fmaxf(v.z, v.w)));
    }
    red[threadIdx.x] = m;
    __syncthreads();
    for (int s = 128; s > 0; s >>= 1) {
        if (threadIdx.x < s) red[threadIdx.x] = fmaxf(red[threadIdx.x], red[threadIdx.x + s]);
        __syncthreads();
    }
    if (threadIdx.x == 0) maxd[0] = red[0];
}

// ---------------- K3: wave-autonomous A-frag MFMA attention GEMM ----------
// Wave wv owns rows [i0+wv*16, +16). Lane (ln,g): adj row i0+wv*16+ln,
// j-chunk g*8..+8 -> w in regs == exact A-fragment (A[m=ln][k=g*8+u]).
// No wA LDS. B tile (hT hi-only) DMA'd to dbuf LDS, swizzled 16B chunks.
// LDS chunk c = f*4 + pc holds hT[f][j0 + (pc^((f>>1)&3))*8 .. +8] at BYTE
// offset c*16.  (R6 bug: read offsets were scaled 2x -> OOB -> inf.)
__global__ __launch_bounds__(256, 3) void k3_attn(const int* __restrict__ adj,
                                                  const __bf16* __restrict__ hT,
                                                  const float* __restrict__ src,
                                                  const float* __restrict__ dst,
                                                  const float* __restrict__ maxd,
                                                  float* __restrict__ num,
                                                  float* __restrict__ den) {
    __shared__ __bf16 bh[2][1024 * 8];   // 2 x 16 KB
    const int t = threadIdx.x;
    const int l = t & 63, wv = t >> 6, ln = l & 15, g = l >> 4;
    const int it = blockIdx.x & 127;
    const int seg = blockIdx.x >> 7;
    const int i0 = it * 64;
    const int jbeg = seg * JSEG;
    const int row = i0 + wv * 16 + ln;
    const float maxdv = maxd[0];
    const float src_r = src[row];
    const float e0 = src_r + maxdv;
    const float m_r = e0 > 0.f ? e0 : ALPHA * e0;   // per-row shift >= row max

    // DMA descriptors: 4 chunks/thread, lane-linear LDS, swizzle on gaddr
    int ga[4], cb[4];
    #pragma unroll
    for (int r = 0; r < 4; ++r) {
        int cbase = r * 256 + wv * 64;
        int c = cbase + l;
        int f = c >> 2;
        int pc = c & 3;
        int jc = pc ^ ((f >> 1) & 3);
        ga[r] = f * NN + jc * 8;        // hi-only hT
        cb[r] = __builtin_amdgcn_readfirstlane(cbase);
    }
    const int* arow = adj + (size_t)row * NN + g * 8;
    const float* drow = dst + g * 8;

    // B-read base (BYTES): f=nt*16+ln -> elem off = f*32 + (g^sw)*8,
    // sw=((f>>1)&3)=((ln>>1)&3); nt stride = 512 elems = 1024 B.
    const int rb = ln * 64 + ((g ^ ((ln >> 1) & 3)) * 16);
    const char* bh0 = (const char*)&bh[0][0] + rb;
    const char* bh1 = (const char*)&bh[1][0] + rb;

    // even/odd prefetch slots (scalar regs — R4 spill lesson)
    int4 a0e, a1e, a0o, a1o;
    float4 d0e, d1e, d0o, d1o;

    // prologue: adjE(0)x4, DMA(0)x4, adjO(1)x4  (issue order = ledger)
    a0e = *(const int4*)(arow + jbeg);
    a1e = *(const int4*)(arow + jbeg + 4);
    d0e = *(const float4*)(drow + jbeg);
    d1e = *(const float4*)(drow + jbeg + 4);
    FENCE;
    #pragma unroll
    for (int r = 0; r < 4; ++r)
        dma16(&hT[ga[r] + jbeg], &bh[0][cb[r] * 8]);
    FENCE;
    a0o = *(const int4*)(arow + jbeg + 32);
    a1o = *(const int4*)(arow + jbeg + 32 + 4);
    d0o = *(const float4*)(drow + jbeg + 32);
    d1o = *(const float4*)(drow + jbeg + 32 + 4);
    FENCE;

    float den_reg = 0.f;
    f32x4 acc[16];
    #pragma unroll
    for (int nt = 0; nt < 16; ++nt) acc[nt] = (f32x4){0.f, 0.f, 0.f, 0.f};

#define K3_WCOMP(A0_, A1_, D0_, D1_, AF_)                                     \
    {                                                                         \
        const int av[8] = {A0_.x, A0_.y, A0_.z, A0_.w,                        \
                           A1_.x, A1_.y, A1_.z, A1_.w};                       \
        const float dv[8] = {D0_.x, D0_.y, D0_.z, D0_.w,                      \
                             D1_.x, D1_.y, D1_.z, D1_.w};                     \
        _Pragma("unroll")                                                     \
        for (int u = 0; u < 8; ++u) {                                         \
            float e = src_r + dv[u];                                          \
            e = e > 0.f ? e : ALPHA * e;                                      \
            float w = (av[u] > 0) ? __expf(e - m_r) : 0.f;                    \
            den_reg += w;                                                     \
            AF_[u] = (__bf16)w;                                               \
        }                                                                     \
    }

#define K3_PREF(A0_, A1_, D0_, D1_, JN_)                                      \
    A0_ = *(const int4*)(arow + (JN_));                                       \
    A1_ = *(const int4*)(arow + (JN_) + 4);                                   \
    D0_ = *(const float4*)(drow + (JN_));                                     \
    D1_ = *(const float4*)(drow + (JN_) + 4);

#define K3_DMA(J1_, P_)                                                       \
    {                                                                         \
        _Pragma("unroll")                                                     \
        for (int r = 0; r < 4; ++r)                                           \
            dma16(&hT[ga[r] + (J1_)], &bh[P_][cb[r] * 8]);                    \
    }

#define K3_MFMA(AF_, BP_)                                                     \
    {                                                                         \
        _Pragma("unroll")                                                     \
        for (int nt = 0; nt < 16; ++nt) {                                     \
            bf16x8 bfr = *(const bf16x8*)((BP_) + nt * 1024);                 \
            acc[nt] = __builtin_amdgcn_mfma_f32_16x16x32_bf16(                \
                AF_, bfr, acc[nt], 0, 0, 0);                                  \
        }                                                                     \
    }

    for (int su = 0; su < STEPS; su += 2) {
        // ---- even half: s = su, even slots, bh[0] ----
        bf16x8 afe;
        K3_WCOMP(a0e, a1e, d0e, d1e, afe);
        {
            const int jn = (su + 2 < STEPS) ? jbeg + (su + 2) * 32 : jbeg;
            K3_PREF(a0e, a1e, d0e, d1e, jn);
        }
        FENCE; VMCNT4; LGKM0; BARRIER;
        K3_DMA(jbeg + (su + 1) * 32, 1);
        FENCE;
        K3_MFMA(afe, bh0);
        // ---- odd half: s = su+1, odd slots, bh[1] ----
        bf16x8 afo;
        K3_WCOMP(a0o, a1o, d0o, d1o, afo);
        {
            const int jn = (su + 3 < STEPS) ? jbeg + (su + 3) * 32 : jbeg;
            K3_PREF(a0o, a1o, d0o, d1o, jn);
        }
        FENCE; VMCNT4; LGKM0; BARRIER;
        {
            const int j2 = (su + 2 < STEPS) ? jbeg + (su + 2) * 32 : jbeg;
            K3_DMA(j2, 0);
        }
        FENCE;
        K3_MFMA(afo, bh1);
    }
    // epilogue: den = reduce over g lanes (xor bits 4,5)
    den_reg += __shfl_xor(den_reg, 16);
    den_reg += __shfl_xor(den_reg, 32);
    if (g == 0) den[(size_t)seg * NN + row] = den_reg;
    // num: C layout col=ln, row m=g*4+rg within wave's 16-row tile
    #pragma unroll
    for (int nt = 0; nt < 16; ++nt)
        #pragma unroll
        for (int rg = 0; rg < 4; ++rg)
            num[((size_t)seg * NN + i0 + wv * 16 + g * 4 + rg) * FF
                + nt * 16 + ln] = acc[nt][rg];
}

// ---------------- K4: out = relu( sum_s num / sum_s den ) -----------------
__global__ __launch_bounds__(256) void k4_out(const float* __restrict__ num,
                                              const float* __restrict__ den,
                                              float* __restrict__ out) {
    size_t f4 = (size_t)blockIdx.x * 256 + threadIdx.x;
    int i = (int)(f4 >> 6);
    int c4 = (int)(f4 & 63) << 2;
    float4 s = make_float4(0.f, 0.f, 0.f, 0.f);
    float d = 0.f;
    #pragma unroll
    for (int sg = 0; sg < SS; ++sg) {
        float4 v = *(const float4*)&num[((size_t)sg * NN + i) * FF + c4];
        s.x += v.x; s.y += v.y; s.z += v.z; s.w += v.w;
        d += den[(size_t)sg * NN + i];
    }
    float inv = 1.f / d;
    float4 o;
    o.x = fmaxf(s.x * inv, 0.f);
    o.y = fmaxf(s.y * inv, 0.f);
    o.z = fmaxf(s.z * inv, 0.f);
    o.w = fmaxf(s.w * inv, 0.f);
    *(float4*)&out[(size_t)i * FF + c4] = o;
}

extern "C" void kernel_launch(void* const* d_in, const int* in_sizes, int n_in,
                              void* d_out, int out_size, void* d_ws, size_t ws_size,
                              hipStream_t stream) {
    const float* X  = (const float*)d_in[0];
    const int*  adj = (const int*)d_in[1];
    const float* W  = (const float*)d_in[2];
    const float* a  = (const float*)d_in[3];
    float* out = (float*)d_out;
    char* ws = (char*)d_ws;

    const size_t off_hT   = 0;
    const size_t off_wt   = off_hT + (size_t)2 * FF * NN * 2;
    const size_t off_src  = off_wt + (size_t)2 * FF * FF * 2;
    const size_t off_dst  = off_src + (size_t)NN * 4;
    const size_t off_maxd = off_dst + (size_t)NN * 4;
    const size_t off_num  = off_maxd + 256;
    const size_t off_den  = off_num + (size_t)SS * NN * FF * 4;

    __bf16* hT_ws = (__bf16*)(ws + off_hT);
    __bf16* wt_ws = (__bf16*)(ws + off_wt);
    float* src_ws = (float*)(ws + off_src);
    float* dst_ws = (float*)(ws + off_dst);
    float* maxd   = (float*)(ws + off_maxd);
    float* num_ws = (float*)(ws + off_num);
    float* den_ws = (float*)(ws + off_den);

    k0_wt<<<dim3(FF / 64, FF / 64), 256, 0, stream>>>(W, wt_ws);
    k1_h<<<NN / 32, 256, 0, stream>>>(X, wt_ws, a, hT_ws, src_ws, dst_ws);
    k2b_max<<<1, 256, 0, stream>>>(dst_ws, maxd);
    k3_attn<<<(NN / 64) * SS, 256, 0, stream>>>(adj, hT_ws, src_ws, dst_ws, maxd,
                                                num_ws, den_ws);
    k4_out<<<(NN * FF / 4) / 256, 256, 0, stream>>>(num_ws, den_ws, out);
}